// Round 2
// baseline (30.864 us; speedup 1.0000x reference)
//
#include <hip/hip_runtime.h>
#include <math.h>

// Problem constants (fixed by the reference setup)
#define NN 16
#define CC 85
#define HH 160
#define WW 160
#define HW_ (HH * WW)        // 25600
#define NHW (NN * HW_)       // 409600

struct Acc {
  double sum_iou;   // sum of iou over m
  double sum_liou;  // sum of (1-iou) over f
  double sum_nll;   // sum of nll over f
  double obj_sum;   // sum of sl1*factor over all cells
  int cnt_m;
  int cnt_f;
  int nperb[NN];
};

__device__ __forceinline__ float wave_sum(float v) {
#pragma unroll
  for (int o = 32; o; o >>= 1) v += __shfl_down(v, o, 64);
  return v;
}

// SIoU variant from the reference (_bbox_iou)
__device__ __forceinline__ float siou(float pcx, float pcy, float pw, float ph,
                                      float gcx, float gcy, float gw, float gh) {
  const float eps = 1e-7f;
  float b1x1 = pcx - pw * 0.5f, b1x2 = pcx + pw * 0.5f;
  float b1y1 = pcy - ph * 0.5f, b1y2 = pcy + ph * 0.5f;
  float b2x1 = gcx - gw * 0.5f, b2x2 = gcx + gw * 0.5f;
  float b2y1 = gcy - gh * 0.5f, b2y2 = gcy + gh * 0.5f;
  float inter = fmaxf(fminf(b1x2, b2x2) - fmaxf(b1x1, b2x1), 0.f) *
                fmaxf(fminf(b1y2, b2y2) - fmaxf(b1y1, b2y1), 0.f);
  float w1 = b1x2 - b1x1, h1 = b1y2 - b1y1 + eps;
  float w2 = b2x2 - b2x1, h2 = b2y2 - b2y1 + eps;
  float uni = w1 * h1 + w2 * h2 - inter + eps;
  float iou = inter / uni;
  float cw = fmaxf(b1x2, b2x2) - fminf(b1x1, b2x1);
  float ch = fmaxf(b1y2, b2y2) - fminf(b1y1, b2y1);
  float s_cw = (b2x1 + b2x2 - b1x1 - b1x2) * 0.5f;
  float s_ch = (b2y1 + b2y2 - b1y1 - b1y2) * 0.5f;
  float sigma = sqrtf(s_cw * s_cw + s_ch * s_ch);
  float sin_a1 = fabsf(s_cw) / sigma;
  float sin_a2 = fabsf(s_ch) / sigma;
  float sin_a = (sin_a1 > 0.70710678f) ? sin_a2 : sin_a1;
  // cos(2*asin(x) - pi/2) == 2*x*sqrt(1-x^2)
  float angle_cost = 2.f * sin_a * sqrtf(fmaxf(1.f - sin_a * sin_a, 0.f));
  float rx = s_cw / cw; rx *= rx;
  float ry = s_ch / ch; ry *= ry;
  float gamma = angle_cost - 2.f;
  float dist = 2.f - expf(gamma * rx) - expf(gamma * ry);
  float ow = fabsf(w1 - w2) / fmaxf(w1, w2);
  float oh = fabsf(h1 - h2) / fmaxf(h1, h2);
  float e1 = 1.f - expf(-ow), e2 = 1.f - expf(-oh);
  float s1 = e1 * e1; s1 *= s1;
  float s2 = e2 * e2; s2 *= s2;
  return iou - 0.5f * (dist + s1 + s2);
}

__device__ __forceinline__ void decode(const float* __restrict__ t6, int q,
                                       int& b, int& cls,
                                       float& gx, float& gy, float& gw, float& gh,
                                       int& gi, int& gj, bool& m) {
  b = (int)t6[0];
  cls = (int)t6[1];
  gx = t6[2] * (float)WW;
  gy = t6[3] * (float)HH;
  gw = t6[4] * (float)WW;
  gh = t6[5] * (float)HH;
  gi = (int)gx + (q & 1);
  gj = (int)gy + (q >> 1);
  // j = min(where(gij<H, gij, 0)) > 0  <=>  both coords in [1, H)
  m = (gi >= 1) && (gi < WW) && (gj >= 1) && (gj < HH);
}

__global__ void k_init(Acc* __restrict__ acc, int* __restrict__ winner,
                       float* __restrict__ tobj, float* __restrict__ factor) {
  int i = blockIdx.x * blockDim.x + threadIdx.x;
  if (i < NHW) {
    winner[i] = -1;
    tobj[i] = 0.f;
    factor[i] = 0.75f;
  }
  if (i == 0) {
    acc->sum_iou = 0.0; acc->sum_liou = 0.0; acc->sum_nll = 0.0; acc->obj_sum = 0.0;
    acc->cnt_m = 0; acc->cnt_f = 0;
    for (int b = 0; b < NN; ++b) acc->nperb[b] = 0;
  }
}

__global__ void k_iou(const float* __restrict__ preds, const float* __restrict__ targets,
                      int M, Acc* __restrict__ acc, float* __restrict__ iou_arr) {
  int k = blockIdx.x * blockDim.x + threadIdx.x;
  int M4 = 4 * M;
  float iou_v = 0.f, mf = 0.f;
  if (k < M4) {
    int mm = k % M, q = k / M;
    int b, cls, gi, gj; float gx, gy, gw, gh; bool m;
    decode(targets + (size_t)mm * 6, q, b, cls, gx, gy, gw, gh, gi, gj, m);
    if (m) {
      const float* p = preds + (size_t)b * CC * HW_ + (size_t)gj * WW + gi;
      float p0 = p[(size_t)1 * HW_];
      float p1 = p[(size_t)2 * HW_];
      float p2 = p[(size_t)3 * HW_];
      float p3 = p[(size_t)4 * HW_];
      float px = tanhf(p0) + (float)gi;
      float py = tanhf(p1) + (float)gj;
      float pw = (1.f / (1.f + expf(-p2))) * (float)WW;
      float ph = (1.f / (1.f + expf(-p3))) * (float)HH;
      iou_v = siou(px, py, pw, ph, gx, gy, gw, gh);
      iou_arr[k] = iou_v;
      mf = 1.f;
    } else {
      iou_arr[k] = -1e30f;
    }
  }
  __shared__ float shS[4], shC[4];
  float s = wave_sum(iou_v), c = wave_sum(mf);
  int lane = threadIdx.x & 63, wid = threadIdx.x >> 6;
  if (lane == 0) { shS[wid] = s; shC[wid] = c; }
  __syncthreads();
  if (threadIdx.x == 0) {
    atomicAdd(&acc->sum_iou, (double)(shS[0] + shS[1] + shS[2] + shS[3]));
    atomicAdd(&acc->cnt_m, (int)(shC[0] + shC[1] + shC[2] + shC[3]));
  }
}

__global__ void k_filter(const float* __restrict__ preds, const float* __restrict__ targets,
                         int M, Acc* __restrict__ acc, const float* __restrict__ iou_arr,
                         int* __restrict__ winner) {
  __shared__ int hist[NN];
  __shared__ float shA[4], shB[4], shC2[4];
  if (threadIdx.x < NN) hist[threadIdx.x] = 0;
  __syncthreads();

  int k = blockIdx.x * blockDim.x + threadIdx.x;
  int M4 = 4 * M;
  float iou_mean = (float)(acc->sum_iou / (double)max(acc->cnt_m, 1));
  float fc = 0.f, liou = 0.f, nllv = 0.f;
  if (k < M4) {
    int mm = k % M, q = k / M;
    int b, cls, gi, gj; float gx, gy, gw, gh; bool m;
    decode(targets + (size_t)mm * 6, q, b, cls, gx, gy, gw, gh, gi, gj, m);
    float iou_v = iou_arr[k];
    if (m && iou_v > iou_mean) {
      fc = 1.f;
      liou = 1.f - iou_v;
      nllv = -logf(preds[(size_t)(b * CC + 5 + cls) * HW_ + (size_t)gj * WW + gi]);
      int idx = b * HW_ + gj * WW + gi;
      atomicMax(&winner[idx], k);   // max-k == numpy last-occurrence-wins
      atomicAdd(&hist[b], 1);
    }
  }
  float a = wave_sum(fc), bb = wave_sum(liou), cc2 = wave_sum(nllv);
  int lane = threadIdx.x & 63, wid = threadIdx.x >> 6;
  if (lane == 0) { shA[wid] = a; shB[wid] = bb; shC2[wid] = cc2; }
  __syncthreads();
  if (threadIdx.x == 0) {
    atomicAdd(&acc->cnt_f, (int)(shA[0] + shA[1] + shA[2] + shA[3]));
    atomicAdd(&acc->sum_liou, (double)(shB[0] + shB[1] + shB[2] + shB[3]));
    atomicAdd(&acc->sum_nll, (double)(shC2[0] + shC2[1] + shC2[2] + shC2[3]));
  }
  if (threadIdx.x < NN && hist[threadIdx.x] > 0)
    atomicAdd(&acc->nperb[threadIdx.x], hist[threadIdx.x]);
}

__global__ void k_scatter(const float* __restrict__ targets, int M,
                          const Acc* __restrict__ acc, const float* __restrict__ iou_arr,
                          const int* __restrict__ winner,
                          float* __restrict__ tobj, float* __restrict__ factor) {
  int k = blockIdx.x * blockDim.x + threadIdx.x;
  int M4 = 4 * M;
  if (k >= M4) return;
  float iou_mean = (float)(acc->sum_iou / (double)max(acc->cnt_m, 1));
  int mm = k % M, q = k / M;
  int b, cls, gi, gj; float gx, gy, gw, gh; bool m;
  decode(targets + (size_t)mm * 6, q, b, cls, gx, gy, gw, gh, gi, gj, m);
  float iou_v = iou_arr[k];
  if (m && iou_v > iou_mean) {
    int idx = b * HW_ + gj * WW + gi;
    if (winner[idx] == k) {
      tobj[idx] = iou_v;
      factor[idx] = (float)HW_ / (float)acc->nperb[b] * 0.25f;
    }
  }
}

__global__ void k_obj(const float* __restrict__ preds, const float* __restrict__ tobj,
                      const float* __restrict__ factor, Acc* __restrict__ acc) {
  int t = blockIdx.x * blockDim.x + threadIdx.x;
  int i0 = t * 4;
  float s = 0.f;
  if (i0 < NHW) {
    int b = i0 / HW_;
    int r = i0 - b * HW_;   // HW_ % 4 == 0, so the 4 elems stay in one batch slab
    float4 p4 = *reinterpret_cast<const float4*>(preds + (size_t)b * CC * HW_ + r);
    float4 t4 = *reinterpret_cast<const float4*>(tobj + i0);
    float4 f4 = *reinterpret_cast<const float4*>(factor + i0);
    float pv[4] = {p4.x, p4.y, p4.z, p4.w};
    float tv[4] = {t4.x, t4.y, t4.z, t4.w};
    float fv[4] = {f4.x, f4.y, f4.z, f4.w};
#pragma unroll
    for (int j = 0; j < 4; ++j) {
      float d = pv[j] - tv[j];
      float ad = fabsf(d);
      float sl1 = (ad < 1.f) ? 0.5f * d * d : (ad - 0.5f);
      s += sl1 * fv[j];
    }
  }
  __shared__ float sh[4];
  float v = wave_sum(s);
  int lane = threadIdx.x & 63, wid = threadIdx.x >> 6;
  if (lane == 0) sh[wid] = v;
  __syncthreads();
  if (threadIdx.x == 0)
    atomicAdd(&acc->obj_sum, (double)(sh[0] + sh[1] + sh[2] + sh[3]));
}

__global__ void k_final(const Acc* __restrict__ acc, float* __restrict__ out) {
  float cf = fmaxf((float)acc->cnt_f, 1.f);
  float iou_loss = (float)acc->sum_liou / cf;
  float cls_loss = (float)acc->sum_nll / cf;
  float obj_loss = (float)(acc->obj_sum / (double)NHW);
  out[0] = iou_loss;
  out[1] = obj_loss;
  out[2] = cls_loss;
  out[3] = iou_loss * 8.f + obj_loss * 16.f + cls_loss;
}

extern "C" void kernel_launch(void* const* d_in, const int* in_sizes, int n_in,
                              void* d_out, int out_size, void* d_ws, size_t ws_size,
                              hipStream_t stream) {
  const float* preds = (const float*)d_in[0];
  const float* targets = (const float*)d_in[1];
  int M = in_sizes[1] / 6;     // 4096
  int M4 = 4 * M;              // 16384

  char* ws = (char*)d_ws;
  Acc* acc = (Acc*)ws;
  size_t off = 256;
  float* iou_arr = (float*)(ws + off); off += (((size_t)M4 * 4) + 255) & ~(size_t)255;
  int* winner = (int*)(ws + off);      off += (size_t)NHW * 4;
  float* tobj = (float*)(ws + off);    off += (size_t)NHW * 4;
  float* factor = (float*)(ws + off);  off += (size_t)NHW * 4;
  // total ~5 MB of d_ws

  const int tb = 256;
  k_init<<<(NHW + tb - 1) / tb, tb, 0, stream>>>(acc, winner, tobj, factor);
  k_iou<<<(M4 + tb - 1) / tb, tb, 0, stream>>>(preds, targets, M, acc, iou_arr);
  k_filter<<<(M4 + tb - 1) / tb, tb, 0, stream>>>(preds, targets, M, acc, iou_arr, winner);
  k_scatter<<<(M4 + tb - 1) / tb, tb, 0, stream>>>(targets, M, acc, iou_arr, winner, tobj, factor);
  k_obj<<<(NHW / 4 + tb - 1) / tb, tb, 0, stream>>>(preds, tobj, factor, acc);
  k_final<<<1, 1, 0, stream>>>(acc, (float*)d_out);
}

// Round 3
// 24.949 us; speedup vs baseline: 1.2371x; 1.2371x over previous
//
#include <hip/hip_runtime.h>
#include <math.h>

// Problem constants (fixed by the reference setup)
#define NN 16
#define CC 85
#define HH 160
#define WW 160
#define HW_ (HH * WW)        // 25600
#define NHW (NN * HW_)       // 409600
#define TB 256
#define GRID1 400            // NHW/4/TB = 400 exactly
#define GRID2 64             // M4/TB = 64 exactly (M=4096)

struct Acc {
  double sum_liou;  // sum of (1-iou) over f        (K2)
  double sum_nll;   // sum of nll over f            (K2)
  double obj_corr;  // scatter-cell correction term (K3)
  int cnt_f;        // (K2)
  int done;         // K3 completion counter
  int nperb[NN];    // (K2)
};

__device__ __forceinline__ float wave_sum(float v) {
#pragma unroll
  for (int o = 32; o; o >>= 1) v += __shfl_down(v, o, 64);
  return v;
}

__device__ __forceinline__ float sl1(float d) {
  float ad = fabsf(d);
  return (ad < 1.f) ? 0.5f * d * d : (ad - 0.5f);
}

// SIoU variant from the reference (_bbox_iou)
__device__ __forceinline__ float siou(float pcx, float pcy, float pw, float ph,
                                      float gcx, float gcy, float gw, float gh) {
  const float eps = 1e-7f;
  float b1x1 = pcx - pw * 0.5f, b1x2 = pcx + pw * 0.5f;
  float b1y1 = pcy - ph * 0.5f, b1y2 = pcy + ph * 0.5f;
  float b2x1 = gcx - gw * 0.5f, b2x2 = gcx + gw * 0.5f;
  float b2y1 = gcy - gh * 0.5f, b2y2 = gcy + gh * 0.5f;
  float inter = fmaxf(fminf(b1x2, b2x2) - fmaxf(b1x1, b2x1), 0.f) *
                fmaxf(fminf(b1y2, b2y2) - fmaxf(b1y1, b2y1), 0.f);
  float w1 = b1x2 - b1x1, h1 = b1y2 - b1y1 + eps;
  float w2 = b2x2 - b2x1, h2 = b2y2 - b2y1 + eps;
  float uni = w1 * h1 + w2 * h2 - inter + eps;
  float iou = inter / uni;
  float cw = fmaxf(b1x2, b2x2) - fminf(b1x1, b2x1);
  float ch = fmaxf(b1y2, b2y2) - fminf(b1y1, b2y1);
  float s_cw = (b2x1 + b2x2 - b1x1 - b1x2) * 0.5f;
  float s_ch = (b2y1 + b2y2 - b1y1 - b1y2) * 0.5f;
  float sigma = sqrtf(s_cw * s_cw + s_ch * s_ch);
  float sin_a1 = fabsf(s_cw) / sigma;
  float sin_a2 = fabsf(s_ch) / sigma;
  float sin_a = (sin_a1 > 0.70710678f) ? sin_a2 : sin_a1;
  // cos(2*asin(x) - pi/2) == 2*x*sqrt(1-x^2)
  float angle_cost = 2.f * sin_a * sqrtf(fmaxf(1.f - sin_a * sin_a, 0.f));
  float rx = s_cw / cw; rx *= rx;
  float ry = s_ch / ch; ry *= ry;
  float gamma = angle_cost - 2.f;
  float dist = 2.f - expf(gamma * rx) - expf(gamma * ry);
  float ow = fabsf(w1 - w2) / fmaxf(w1, w2);
  float oh = fabsf(h1 - h2) / fmaxf(h1, h2);
  float e1 = 1.f - expf(-ow), e2 = 1.f - expf(-oh);
  float s1 = e1 * e1; s1 *= s1;
  float s2 = e2 * e2; s2 *= s2;
  return iou - 0.5f * (dist + s1 + s2);
}

__device__ __forceinline__ void decode(const float* __restrict__ t6, int q,
                                       int& b, int& cls,
                                       float& gx, float& gy, float& gw, float& gh,
                                       int& gi, int& gj, bool& m) {
  b = (int)t6[0];
  cls = (int)t6[1];
  gx = t6[2] * (float)WW;
  gy = t6[3] * (float)HH;
  gw = t6[4] * (float)WW;
  gh = t6[5] * (float)HH;
  gi = (int)gx + (q & 1);
  gj = (int)gy + (q >> 1);
  m = (gi >= 1) && (gi < WW) && (gj >= 1) && (gj < HH);
}

// K1: acc zero + winner init + base obj partial + per-anchor SIoU.
// All independent; reductions go to per-block partial arrays (no atomics
// racing the zeroing).
__global__ void k1(const float* __restrict__ preds, const float* __restrict__ targets,
                   int M, Acc* __restrict__ acc, float* __restrict__ iou_arr,
                   int* __restrict__ winner,
                   float* __restrict__ part_obj, float* __restrict__ part_iou,
                   float* __restrict__ part_cnt) {
  int t = blockIdx.x * blockDim.x + threadIdx.x;
  if (t == 0) {
    acc->sum_liou = 0.0; acc->sum_nll = 0.0; acc->obj_corr = 0.0;
    acc->cnt_f = 0; acc->done = 0;
    for (int b = 0; b < NN; ++b) acc->nperb[b] = 0;
  }

  // --- cells: winner init + base obj term (tobj=0, factor folded later) ---
  int i0 = t * 4;
  float objs = 0.f;
  {
    *reinterpret_cast<int4*>(winner + i0) = make_int4(-1, -1, -1, -1);
    int b = i0 / HW_;
    int r = i0 - b * HW_;      // HW_ % 4 == 0 -> stays in one batch slab
    float4 p4 = *reinterpret_cast<const float4*>(preds + (size_t)b * CC * HW_ + r);
    objs = sl1(p4.x) + sl1(p4.y) + sl1(p4.z) + sl1(p4.w);
  }

  // --- anchors: SIoU ---
  int M4 = 4 * M;
  float iou_v = 0.f, mf = 0.f;
  if (t < M4) {
    int mm = t % M, q = t / M;
    int b, cls, gi, gj; float gx, gy, gw, gh; bool m;
    decode(targets + (size_t)mm * 6, q, b, cls, gx, gy, gw, gh, gi, gj, m);
    if (m) {
      const float* p = preds + (size_t)b * CC * HW_ + (size_t)gj * WW + gi;
      float p0 = p[(size_t)1 * HW_];
      float p1 = p[(size_t)2 * HW_];
      float p2 = p[(size_t)3 * HW_];
      float p3 = p[(size_t)4 * HW_];
      float px = tanhf(p0) + (float)gi;
      float py = tanhf(p1) + (float)gj;
      float pw = (1.f / (1.f + expf(-p2))) * (float)WW;
      float ph = (1.f / (1.f + expf(-p3))) * (float)HH;
      iou_v = siou(px, py, pw, ph, gx, gy, gw, gh);
      iou_arr[t] = iou_v;
      mf = 1.f;
    } else {
      iou_arr[t] = -1e30f;
    }
  }

  __shared__ float shO[4], shI[4], shC[4];
  float o = wave_sum(objs), s = wave_sum(iou_v), c = wave_sum(mf);
  int lane = threadIdx.x & 63, wid = threadIdx.x >> 6;
  if (lane == 0) { shO[wid] = o; shI[wid] = s; shC[wid] = c; }
  __syncthreads();
  if (threadIdx.x == 0) {
    part_obj[blockIdx.x] = shO[0] + shO[1] + shO[2] + shO[3];
    part_iou[blockIdx.x] = shI[0] + shI[1] + shI[2] + shI[3];
    part_cnt[blockIdx.x] = shC[0] + shC[1] + shC[2] + shC[3];
  }
}

__device__ __forceinline__ float compute_iou_mean(const float* __restrict__ part_iou,
                                                  const float* __restrict__ part_cnt,
                                                  float* shS, float* shC) {
  float s = 0.f, c = 0.f;
  for (int i = threadIdx.x; i < GRID1; i += TB) { s += part_iou[i]; c += part_cnt[i]; }
  s = wave_sum(s); c = wave_sum(c);
  int lane = threadIdx.x & 63, wid = threadIdx.x >> 6;
  if (lane == 0) { shS[wid] = s; shC[wid] = c; }
  __syncthreads();
  return (shS[0] + shS[1] + shS[2] + shS[3]) /
         fmaxf(shC[0] + shC[1] + shC[2] + shC[3], 1.f);
}

// K2: filter — cnt_f, sum(1-iou), sum(nll), nperb histogram, winner atomicMax
__global__ void k2(const float* __restrict__ preds, const float* __restrict__ targets,
                   int M, Acc* __restrict__ acc, const float* __restrict__ iou_arr,
                   int* __restrict__ winner,
                   const float* __restrict__ part_iou, const float* __restrict__ part_cnt) {
  __shared__ float shS[4], shC[4];
  __shared__ int hist[NN];
  if (threadIdx.x < NN) hist[threadIdx.x] = 0;
  float iou_mean = compute_iou_mean(part_iou, part_cnt, shS, shC);
  __syncthreads();

  int k = blockIdx.x * blockDim.x + threadIdx.x;
  int mm = k % M, q = k / M;
  int b, cls, gi, gj; float gx, gy, gw, gh; bool m;
  decode(targets + (size_t)mm * 6, q, b, cls, gx, gy, gw, gh, gi, gj, m);
  float iou_v = iou_arr[k];
  float fc = 0.f, liou = 0.f, nllv = 0.f;
  if (m && iou_v > iou_mean) {
    fc = 1.f;
    liou = 1.f - iou_v;
    nllv = -logf(preds[(size_t)(b * CC + 5 + cls) * HW_ + (size_t)gj * WW + gi]);
    int idx = b * HW_ + gj * WW + gi;
    atomicMax(&winner[idx], k);     // max-k == numpy last-occurrence-wins
    atomicAdd(&hist[b], 1);
  }
  __shared__ float shA[4], shB[4], shD[4];
  float a = wave_sum(fc), bb = wave_sum(liou), dd = wave_sum(nllv);
  int lane = threadIdx.x & 63, wid = threadIdx.x >> 6;
  if (lane == 0) { shA[wid] = a; shB[wid] = bb; shD[wid] = dd; }
  __syncthreads();
  if (threadIdx.x == 0) {
    atomicAdd(&acc->cnt_f, (int)(shA[0] + shA[1] + shA[2] + shA[3]));
    atomicAdd(&acc->sum_liou, (double)(shB[0] + shB[1] + shB[2] + shB[3]));
    atomicAdd(&acc->sum_nll, (double)(shD[0] + shD[1] + shD[2] + shD[3]));
  }
  if (threadIdx.x < NN && hist[threadIdx.x] > 0)
    atomicAdd(&acc->nperb[threadIdx.x], hist[threadIdx.x]);
}

// K3: per-winner obj correction + last-block final combine
__global__ void k3(const float* __restrict__ preds, const float* __restrict__ targets,
                   int M, Acc* __restrict__ acc, const float* __restrict__ iou_arr,
                   const int* __restrict__ winner,
                   const float* __restrict__ part_iou, const float* __restrict__ part_cnt,
                   const float* __restrict__ part_obj, float* __restrict__ out) {
  __shared__ float shS[4], shC[4];
  float iou_mean = compute_iou_mean(part_iou, part_cnt, shS, shC);
  __syncthreads();

  int k = blockIdx.x * blockDim.x + threadIdx.x;
  int mm = k % M, q = k / M;
  int b, cls, gi, gj; float gx, gy, gw, gh; bool m;
  decode(targets + (size_t)mm * 6, q, b, cls, gx, gy, gw, gh, gi, gj, m);
  float iou_v = iou_arr[k];
  float corr = 0.f;
  if (m && iou_v > iou_mean) {
    int idx = b * HW_ + gj * WW + gi;
    if (winner[idx] == k) {
      float p = preds[(size_t)b * CC * HW_ + (size_t)gj * WW + gi];
      float fval = (float)HW_ / (float)acc->nperb[b] * 0.25f;
      corr = sl1(p - iou_v) * fval - sl1(p) * 0.75f;
    }
  }
  __shared__ float shR[4];
  float r = wave_sum(corr);
  int lane = threadIdx.x & 63, wid = threadIdx.x >> 6;
  if (lane == 0) shR[wid] = r;
  __syncthreads();
  if (threadIdx.x == 0)
    atomicAdd(&acc->obj_corr, (double)(shR[0] + shR[1] + shR[2] + shR[3]));

  // completion detection
  __shared__ int lastflag;
  __threadfence();
  if (threadIdx.x == 0) {
    int prev = __hip_atomic_fetch_add(&acc->done, 1, __ATOMIC_ACQ_REL,
                                      __HIP_MEMORY_SCOPE_AGENT);
    lastflag = (prev == (int)gridDim.x - 1) ? 1 : 0;
  }
  __syncthreads();
  if (lastflag) {
    float s = 0.f;
    for (int i = threadIdx.x; i < GRID1; i += TB) s += part_obj[i];
    s = wave_sum(s);
    __shared__ float shF[4];
    if (lane == 0) shF[wid] = s;
    __syncthreads();
    if (threadIdx.x == 0) {
      double obj_base = (double)(shF[0] + shF[1] + shF[2] + shF[3]);
      double corr_tot = __hip_atomic_load(&acc->obj_corr, __ATOMIC_RELAXED,
                                          __HIP_MEMORY_SCOPE_AGENT);
      float cf = fmaxf((float)acc->cnt_f, 1.f);
      float iou_loss = (float)acc->sum_liou / cf;
      float cls_loss = (float)acc->sum_nll / cf;
      float obj_loss = (float)((0.75 * obj_base + corr_tot) / (double)NHW);
      out[0] = iou_loss;
      out[1] = obj_loss;
      out[2] = cls_loss;
      out[3] = iou_loss * 8.f + obj_loss * 16.f + cls_loss;
    }
  }
}

extern "C" void kernel_launch(void* const* d_in, const int* in_sizes, int n_in,
                              void* d_out, int out_size, void* d_ws, size_t ws_size,
                              hipStream_t stream) {
  const float* preds = (const float*)d_in[0];
  const float* targets = (const float*)d_in[1];
  int M = in_sizes[1] / 6;     // 4096
  int M4 = 4 * M;              // 16384

  char* ws = (char*)d_ws;
  Acc* acc = (Acc*)ws;
  size_t off = 256;
  float* iou_arr = (float*)(ws + off);  off += (((size_t)M4 * 4) + 255) & ~(size_t)255;
  int* winner   = (int*)(ws + off);     off += (size_t)NHW * 4;
  float* part_obj = (float*)(ws + off); off += GRID1 * 4;
  float* part_iou = (float*)(ws + off); off += GRID1 * 4;
  float* part_cnt = (float*)(ws + off); off += GRID1 * 4;
  // total ~1.8 MB of d_ws

  k1<<<GRID1, TB, 0, stream>>>(preds, targets, M, acc, iou_arr, winner,
                               part_obj, part_iou, part_cnt);
  k2<<<GRID2, TB, 0, stream>>>(preds, targets, M, acc, iou_arr, winner,
                               part_iou, part_cnt);
  k3<<<GRID2, TB, 0, stream>>>(preds, targets, M, acc, iou_arr, winner,
                               part_iou, part_cnt, part_obj, (float*)d_out);
}